// Round 1
// baseline (1507.434 us; speedup 1.0000x reference)
//
#include <hip/hip_runtime.h>
#include <hip/hip_bf16.h>

typedef unsigned short u16;
typedef unsigned int u32;
typedef __attribute__((ext_vector_type(4))) float f32x4;
typedef __attribute__((ext_vector_type(8))) short bf16x8;

#define WLOOP (2.0f/3.0f - 1.0f)      /* -1/3 */
#define WEDGE (-(2.0f/3.0f))          /* -(2/lambda_max) */

__device__ __forceinline__ float bf2f(u16 h){ u32 u = ((u32)h)<<16; float f; __builtin_memcpy(&f,&u,4); return f; }
__device__ __forceinline__ u16 f2bf(float f){ u32 u; __builtin_memcpy(&u,&f,4); u32 r = u + 0x7fffu + ((u>>16)&1u); return (u16)(r>>16); }

__device__ __forceinline__ void async16(u16* lds, const u16* g){
  __builtin_amdgcn_global_load_lds((const __attribute__((address_space(1))) u32*)g,
                                   (__attribute__((address_space(3))) u32*)lds, 16, 0, 0);
}

// ---------------- graph prep ----------------
__global__ void k_hist(const int* __restrict__ ei, int E, int* cntf, int* cntb){
  int e = blockIdx.x*256 + threadIdx.x; if (e>=E) return;
  atomicAdd(&cntf[ei[e]],1); atomicAdd(&cntb[ei[E+e]],1);
}
__global__ void k_dinv(const int* __restrict__ cntf, float* dinv, int N){
  int n = blockIdx.x*256+threadIdx.x; if(n>=N) return;
  int d = cntf[n]; dinv[n] = d>0 ? rsqrtf((float)d) : 0.f;
}
__global__ void k_scanA(const int* __restrict__ cnt, int* excl, int* bsum, int n){
  __shared__ int sh[256]; int i = blockIdx.x*256+threadIdx.x;
  int v = (i<n)? cnt[i]:0; sh[threadIdx.x]=v; __syncthreads();
  for (int off=1; off<256; off<<=1){
    int t = (threadIdx.x>=off)? sh[threadIdx.x-off]:0; __syncthreads();
    sh[threadIdx.x]+=t; __syncthreads();
  }
  if (i<n) excl[i]=sh[threadIdx.x]-v;
  if (threadIdx.x==255) bsum[blockIdx.x]=sh[255];
}
__global__ void k_scanB(int* bsum, int nb, int* total){
  __shared__ int sh[512]; int t = threadIdx.x;
  int v = (t<nb)? bsum[t]:0; sh[t]=v; __syncthreads();
  for(int off=1; off<512; off<<=1){
    int a = (t>=off)? sh[t-off]:0; __syncthreads();
    sh[t]+=a; __syncthreads();
  }
  if (t<nb) bsum[t]=sh[t]-v;
  if (t==511) *total = sh[511];
}
__global__ void k_scanC(int* excl, const int* __restrict__ bsum, int n, int* cur){
  int i = blockIdx.x*256+threadIdx.x; if(i>=n) return;
  int v = excl[i]+bsum[blockIdx.x]; excl[i]=v; cur[i]=v;
}
__global__ void k_fill(const int* __restrict__ ei, int E, const float* __restrict__ dinv,
                       int* curf, int* curb, int* sf, float* wf, int* sb, float* wb){
  int e = blockIdx.x*256+threadIdx.x; if(e>=E) return;
  int r = ei[e], c = ei[E+e];
  float w = WEDGE * dinv[r]*dinv[c];
  int pf = atomicAdd(&curf[r],1); sf[pf]=c; wf[pf]=w;
  int pb = atomicAdd(&curb[c],1); sb[pb]=r; wb[pb]=w;
}

// ---------------- layer 1 (scalar cheb) ----------------
__global__ void k_sprop(const float* __restrict__ t1f, const float* __restrict__ t0f, float* df,
                        const float* __restrict__ t1b, const float* __restrict__ t0b, float* db,
                        const int* __restrict__ offf, const int* __restrict__ sfa, const float* __restrict__ wfa,
                        const int* __restrict__ offb, const int* __restrict__ sba, const float* __restrict__ wba,
                        int N){
  int i = blockIdx.x*256+threadIdx.x;
  int dir = 0; if (i >= N){ i -= N; dir = 1; }
  if (i >= N) return;
  const float* t1; const float* t0; float* d; const int* off; const int* s; const float* w;
  if (dir==0){ t1=t1f; t0=t0f; d=df; off=offf; s=sfa; w=wfa; }
  else       { t1=t1b; t0=t0b; d=db; off=offb; s=sba; w=wba; }
  float a = WLOOP * t1[i];
  int e1 = off[i+1];
  for (int e=off[i]; e<e1; ++e) a += w[e]*t1[s[e]];
  d[i] = t0 ? (2.f*a - t0[i]) : a;
}

__global__ void k_expand(const float* __restrict__ x,
   const float* __restrict__ cf1, const float* __restrict__ cf2, const float* __restrict__ cf3, const float* __restrict__ cf4,
   const float* __restrict__ cb1, const float* __restrict__ cb2, const float* __restrict__ cb3, const float* __restrict__ cb4,
   const float* __restrict__ W1f, const float* __restrict__ b1f,
   const float* __restrict__ W1b, const float* __restrict__ b1b,
   u16* __restrict__ T, int N){
  __shared__ float swf[640], swb[640], sbias[128];
  int tid = threadIdx.x;
  for (int i=tid;i<640;i+=256){ swf[i]=W1f[i]; swb[i]=W1b[i]; }
  if (tid<128) sbias[tid]=b1f[tid]+b1b[tid];
  __syncthreads();
  int j = tid & 127; int n = blockIdx.x*2 + (tid>>7);
  if (n>=N) return;
  float xx = x[n];
  float acc = sbias[j] + xx*(swf[j]+swb[j]);
  acc += cf1[n]*swf[128+j]; acc += cf2[n]*swf[256+j]; acc += cf3[n]*swf[384+j]; acc += cf4[n]*swf[512+j];
  acc += cb1[n]*swb[128+j]; acc += cb2[n]*swb[256+j]; acc += cb3[n]*swb[384+j]; acc += cb4[n]*swb[512+j];
  T[(size_t)n*1152 + j] = f2bf(fmaxf(acc,0.f));
}

// ---------------- layer 2 vector props (bf16 rows, fp32 accum) ----------------
__global__ void k_vprop(u16* __restrict__ T,
   const int* __restrict__ offf, const int* __restrict__ sfa, const float* __restrict__ wfa,
   const int* __restrict__ offb, const int* __restrict__ sba, const float* __restrict__ wba,
   int ssf, int dsf, int psf, int ssb, int dsb, int psb, int N){
  int gid = blockIdx.x*256 + threadIdx.x;
  int wid = gid>>6, l = threadIdx.x & 63;
  int dir = 0; if (wid >= N){ wid -= N; dir = 1; }
  if (wid >= N) return;
  const int* off; const int* s; const float* w; int ss,ds,ps;
  if (!dir){ off=offf;s=sfa;w=wfa;ss=ssf;ds=dsf;ps=psf; }
  else     { off=offb;s=sba;w=wba;ss=ssb;ds=dsb;ps=psb; }
  u32 u = *(const u32*)(T + ((size_t)wid*1152 + ss*128) + 2*l);
  float a0 = WLOOP*bf2f(u&0xffff), a1 = WLOOP*bf2f(u>>16);
  int e1 = off[wid+1];
  for (int e=off[wid]; e<e1; ++e){
    int sn = s[e]; float we = w[e];
    u32 ug = *(const u32*)(T + ((size_t)sn*1152 + ss*128) + 2*l);
    a0 += we*bf2f(ug&0xffff); a1 += we*bf2f(ug>>16);
  }
  float r0=a0, r1=a1;
  if (ps >= 0){
    u32 up = *(const u32*)(T + ((size_t)wid*1152 + ps*128) + 2*l);
    r0 = 2.f*a0 - bf2f(up&0xffff); r1 = 2.f*a1 - bf2f(up>>16);
  }
  *(u32*)(T + ((size_t)wid*1152 + ds*128) + 2*l) = ((u32)f2bf(r1)<<16) | (u32)f2bf(r0);
}

// ---------------- weight prep ----------------
__global__ void k_wprep(const float* __restrict__ W2f, const float* __restrict__ W2b,
                        const float* __restrict__ b2f, const float* __restrict__ b2b,
                        u16* __restrict__ Wt, float* __restrict__ bias2){
  int i = blockIdx.x*256+threadIdx.x;
  if (i < 512) bias2[i] = b2f[i]+b2b[i];
  if (i >= 512*1152) return;
  int j = i/1152, kc = i - j*1152;
  int s2 = kc>>7, c = kc&127;
  float v;
  if (s2==0)      v = W2f[c*512+j] + W2b[c*512+j];
  else if (s2<5)  v = W2f[(s2*128+c)*512 + j];
  else            v = W2b[((s2-4)*128+c)*512 + j];
  Wt[i] = f2bf(v);
}

// ---------------- pooled GEMM: T[M x 1152] @ Wt^T -> relu -> segment-sum ----------------
__global__ __launch_bounds__(256) void k_gemm(const u16* __restrict__ T, const u16* __restrict__ Wt,
                        const float* __restrict__ bias2, const int* __restrict__ batch,
                        float* __restrict__ outp, int Mvalid){
  __shared__ u16 Al[128*64];
  __shared__ u16 Bl[128*64];
  int bid = blockIdx.x;
  int bn = bid & 3, bm = bid >> 2;
  int tid = threadIdx.x, w = tid>>6, l = tid&63;
  int wr = w>>1, wc = w&1;
  int hi = l>>4, lo = l&15;

  f32x4 acc[4][4];
  #pragma unroll
  for (int m=0;m<4;m++)
    #pragma unroll
    for (int n=0;n<4;n++){ acc[m][n][0]=0.f; acc[m][n][1]=0.f; acc[m][n][2]=0.f; acc[m][n][3]=0.f; }

  int ldsoff[4], gA[4], gB[4];
  #pragma unroll
  for (int i=0;i<4;i++){
    int r0 = (w*4+i)*8;
    int r  = r0 + (l>>3);
    int sc = (l&7) ^ (r&7);            // source chunk pre-swizzle (T2 / G4)
    ldsoff[i] = r0*64;
    gA[i] = (bm*128 + r)*1152 + sc*8;
    gB[i] = (bn*128 + r)*1152 + sc*8;
  }
  int rA[4], rB[4];
  #pragma unroll
  for (int m=0;m<4;m++){ rA[m] = wr*64 + m*16 + lo; rB[m] = wc*64 + m*16 + lo; }

  for (int kk=0; kk<1152; kk+=64){
    __syncthreads();
    #pragma unroll
    for (int i=0;i<4;i++){
      async16(&Al[ldsoff[i]], T  + gA[i] + kk);
      async16(&Bl[ldsoff[i]], Wt + gB[i] + kk);
    }
    __syncthreads();
    #pragma unroll
    for (int ks=0; ks<2; ++ks){
      bf16x8 af[4], bfr[4];
      #pragma unroll
      for (int m=0;m<4;m++){
        int ch = (ks*4 + hi) ^ (rA[m]&7);
        af[m] = *(const bf16x8*)&Al[rA[m]*64 + ch*8];
      }
      #pragma unroll
      for (int n=0;n<4;n++){
        int ch = (ks*4 + hi) ^ (rB[n]&7);
        bfr[n] = *(const bf16x8*)&Bl[rB[n]*64 + ch*8];
      }
      #pragma unroll
      for (int m=0;m<4;m++)
        #pragma unroll
        for (int n=0;n<4;n++)
          acc[m][n] = __builtin_amdgcn_mfma_f32_16x16x32_bf16(af[m], bfr[n], acc[m][n], 0, 0, 0);
    }
  }

  // epilogue: bias + relu + segment-sum into pool (batch sorted -> run-length combine)
  #pragma unroll
  for (int m=0;m<4;m++){
    int rbase = bm*128 + wr*64 + m*16 + hi*4;
    #pragma unroll
    for (int n=0;n<4;n++){
      int col = bn*128 + wc*64 + n*16 + lo;
      float bc = bias2[col];
      f32x4 v = acc[m][n];
      int cur = -1; float ssum = 0.f;
      #pragma unroll
      for (int j2=0;j2<4;j2++){
        int row = rbase + j2;
        if (row < Mvalid){
          float val = fmaxf(v[j2] + bc, 0.f);
          int bg = batch[row];
          if (bg != cur){ if (cur >= 0) atomicAdd(&outp[(cur<<9) + col], ssum); cur = bg; ssum = 0.f; }
          ssum += val;
        }
      }
      if (cur >= 0) atomicAdd(&outp[(cur<<9) + col], ssum);
    }
  }
}

__global__ void k_count(const int* __restrict__ batch, int* cg, int N){
  int n = blockIdx.x*256+threadIdx.x; if (n<N) atomicAdd(&cg[batch[n]],1);
}
__global__ void k_div(float* out, const int* __restrict__ cg, int total){
  int i = blockIdx.x*256+threadIdx.x; if (i>=total) return;
  int g = i>>9; out[i] /= fmaxf((float)cg[g], 1.f);
}

extern "C" void kernel_launch(void* const* d_in, const int* in_sizes, int n_in,
                              void* d_out, int out_size, void* d_ws, size_t ws_size,
                              hipStream_t stream) {
  const float* x   = (const float*)d_in[0];
  const int*   ei  = (const int*)d_in[1];
  const int*   bat = (const int*)d_in[2];
  const float* W1f = (const float*)d_in[3];
  const float* b1f = (const float*)d_in[4];
  const float* W1b = (const float*)d_in[5];
  const float* b1b = (const float*)d_in[6];
  const float* W2f = (const float*)d_in[7];
  const float* b2f = (const float*)d_in[8];
  const float* W2b = (const float*)d_in[9];
  const float* b2b = (const float*)d_in[10];

  const int N  = in_sizes[0];
  const int E  = in_sizes[1] / 2;
  const int NP = ((N + 127)/128)*128;

  // ---- ws layout ----
  size_t p = 0;
  auto A = [&](size_t sz){ size_t r = p; p += (sz + 255) & ~(size_t)255; return r; };
  size_t o_cnt  = A(2*(size_t)N*4);          // cnt_f | cnt_b
  size_t o_offf = A(((size_t)N+1)*4);
  size_t o_offb = A(((size_t)N+1)*4);
  size_t o_curf = A((size_t)N*4);
  size_t o_curb = A((size_t)N*4);
  size_t o_bsum = A(512*4);
  size_t o_dinv = A((size_t)N*4);
  size_t o_csf  = A((size_t)E*4);
  size_t o_cwf  = A((size_t)E*4);
  size_t o_csb  = A((size_t)E*4);
  size_t o_cwb  = A((size_t)E*4);
  size_t o_cf   = A(8*(size_t)N*4);          // cf1..4, cb1..4
  size_t o_Wt   = A((size_t)512*1152*2);
  size_t o_b2   = A(512*4);
  size_t o_cg   = A(64*4);
  size_t o_T    = A((size_t)NP*1152*2);
  if (p > ws_size) return;  // ws too small: bail (visible as validation failure)

  char* ws = (char*)d_ws;
  int*   cnt_f = (int*)(ws + o_cnt);
  int*   cnt_b = cnt_f + N;
  int*   off_f = (int*)(ws + o_offf);
  int*   off_b = (int*)(ws + o_offb);
  int*   cur_f = (int*)(ws + o_curf);
  int*   cur_b = (int*)(ws + o_curb);
  int*   bsum  = (int*)(ws + o_bsum);
  float* dinv  = (float*)(ws + o_dinv);
  int*   csf   = (int*)(ws + o_csf);
  float* cwf   = (float*)(ws + o_cwf);
  int*   csb   = (int*)(ws + o_csb);
  float* cwb   = (float*)(ws + o_cwb);
  float* cf1   = (float*)(ws + o_cf);
  float* cf2   = cf1 + N; float* cf3 = cf2 + N; float* cf4 = cf3 + N;
  float* cb1   = cf4 + N; float* cb2 = cb1 + N; float* cb3 = cb2 + N; float* cb4 = cb3 + N;
  u16*   Wt    = (u16*)(ws + o_Wt);
  float* bias2 = (float*)(ws + o_b2);
  int*   cg    = (int*)(ws + o_cg);
  u16*   T     = (u16*)(ws + o_T);
  float* outp  = (float*)d_out;

  const int nbN = (N + 255)/256;
  const int nbE = (E + 255)/256;
  const int nb2N = (2*N + 255)/256;

  // zero-init accumulators + T pad rows
  hipMemsetAsync(cnt_f, 0, 2*(size_t)N*4, stream);
  hipMemsetAsync(cg, 0, 64*4, stream);
  hipMemsetAsync(d_out, 0, (size_t)out_size*4, stream);
  if (NP > N) hipMemsetAsync(T + (size_t)N*1152, 0, (size_t)(NP-N)*1152*2, stream);

  // graph prep
  k_hist<<<nbE,256,0,stream>>>(ei, E, cnt_f, cnt_b);
  k_dinv<<<nbN,256,0,stream>>>(cnt_f, dinv, N);
  k_scanA<<<nbN,256,0,stream>>>(cnt_f, off_f, bsum, N);
  k_scanB<<<1,512,0,stream>>>(bsum, nbN, off_f + N);
  k_scanC<<<nbN,256,0,stream>>>(off_f, bsum, N, cur_f);
  k_scanA<<<nbN,256,0,stream>>>(cnt_b, off_b, bsum, N);
  k_scanB<<<1,512,0,stream>>>(bsum, nbN, off_b + N);
  k_scanC<<<nbN,256,0,stream>>>(off_b, bsum, N, cur_b);
  k_fill<<<nbE,256,0,stream>>>(ei, E, dinv, cur_f, cur_b, csf, cwf, csb, cwb);

  // layer 1 scalar chebyshev
  k_sprop<<<nb2N,256,0,stream>>>(x,   nullptr, cf1,  x,   nullptr, cb1, off_f,csf,cwf, off_b,csb,cwb, N);
  k_sprop<<<nb2N,256,0,stream>>>(cf1, x,       cf2,  cb1, x,       cb2, off_f,csf,cwf, off_b,csb,cwb, N);
  k_sprop<<<nb2N,256,0,stream>>>(cf2, cf1,     cf3,  cb2, cb1,     cb3, off_f,csf,cwf, off_b,csb,cwb, N);
  k_sprop<<<nb2N,256,0,stream>>>(cf3, cf2,     cf4,  cb3, cb2,     cb4, off_f,csf,cwf, off_b,csb,cwb, N);
  k_expand<<<(N+1)/2,256,0,stream>>>(x, cf1,cf2,cf3,cf4, cb1,cb2,cb3,cb4, W1f,b1f,W1b,b1b, T, N);

  // weights for fused GEMM
  k_wprep<<<(512*1152+255)/256,256,0,stream>>>(W2f, W2b, b2f, b2b, Wt, bias2);

  // layer 2 vector chebyshev: slots 0=h, 1..4=fwd, 5..8=bwd
  const int vb = (2*N*64 + 255)/256;
  k_vprop<<<vb,256,0,stream>>>(T, off_f,csf,cwf, off_b,csb,cwb, 0,1,-1, 0,5,-1, N);
  k_vprop<<<vb,256,0,stream>>>(T, off_f,csf,cwf, off_b,csb,cwb, 1,2, 0, 5,6, 0, N);
  k_vprop<<<vb,256,0,stream>>>(T, off_f,csf,cwf, off_b,csb,cwb, 2,3, 1, 6,7, 5, N);
  k_vprop<<<vb,256,0,stream>>>(T, off_f,csf,cwf, off_b,csb,cwb, 3,4, 2, 7,8, 6, N);

  // pooled GEMM + mean
  k_count<<<nbN,256,0,stream>>>(bat, cg, N);
  k_gemm<<<(NP/128)*4,256,0,stream>>>(T, Wt, bias2, bat, outp, N);
  k_div<<<(out_size+255)/256,256,0,stream>>>(outp, cg, out_size);
}

// Round 2
// 1000.777 us; speedup vs baseline: 1.5063x; 1.5063x over previous
//
#include <hip/hip_runtime.h>
#include <hip/hip_bf16.h>

typedef unsigned short u16;
typedef unsigned int u32;
typedef __attribute__((ext_vector_type(4))) float f32x4;
typedef __attribute__((ext_vector_type(8))) short bf16x8;

#define WLOOP (2.0f/3.0f - 1.0f)      /* -1/3 */
#define WEDGE (-(2.0f/3.0f))          /* -(2/lambda_max) */

__device__ __forceinline__ float bf2f(u16 h){ u32 u = ((u32)h)<<16; float f; __builtin_memcpy(&f,&u,4); return f; }
__device__ __forceinline__ u16 f2bf(float f){ u32 u; __builtin_memcpy(&u,&f,4); u32 r = u + 0x7fffu + ((u>>16)&1u); return (u16)(r>>16); }

__device__ __forceinline__ void async16(u16* lds, const u16* g){
  __builtin_amdgcn_global_load_lds((const __attribute__((address_space(1))) u32*)g,
                                   (__attribute__((address_space(3))) u32*)lds, 16, 0, 0);
}

// ---------------- graph prep ----------------
__global__ void k_hist(const int* __restrict__ ei, int E, int* cntf, int* cntb){
  int e = blockIdx.x*256 + threadIdx.x; if (e>=E) return;
  atomicAdd(&cntf[ei[e]],1); atomicAdd(&cntb[ei[E+e]],1);
}
__global__ void k_dinv(const int* __restrict__ cntf, float* dinv, int N){
  int n = blockIdx.x*256+threadIdx.x; if(n>=N) return;
  int d = cntf[n]; dinv[n] = d>0 ? rsqrtf((float)d) : 0.f;
}
__global__ void k_scanA(const int* __restrict__ cnt, int* excl, int* bsum, int n){
  __shared__ int sh[256]; int i = blockIdx.x*256+threadIdx.x;
  int v = (i<n)? cnt[i]:0; sh[threadIdx.x]=v; __syncthreads();
  for (int off=1; off<256; off<<=1){
    int t = (threadIdx.x>=off)? sh[threadIdx.x-off]:0; __syncthreads();
    sh[threadIdx.x]+=t; __syncthreads();
  }
  if (i<n) excl[i]=sh[threadIdx.x]-v;
  if (threadIdx.x==255) bsum[blockIdx.x]=sh[255];
}
__global__ void k_scanB(int* bsum, int nb, int* total){
  __shared__ int sh[512]; int t = threadIdx.x;
  int v = (t<nb)? bsum[t]:0; sh[t]=v; __syncthreads();
  for(int off=1; off<512; off<<=1){
    int a = (t>=off)? sh[t-off]:0; __syncthreads();
    sh[t]+=a; __syncthreads();
  }
  if (t<nb) bsum[t]=sh[t]-v;
  if (t==511) *total = sh[511];
}
__global__ void k_scanC(int* excl, const int* __restrict__ bsum, int n, int* cur){
  int i = blockIdx.x*256+threadIdx.x; if(i>=n) return;
  int v = excl[i]+bsum[blockIdx.x]; excl[i]=v; cur[i]=v;
}
__global__ void k_fill(const int* __restrict__ ei, int E, const float* __restrict__ dinv,
                       int* curf, int* curb, int* sf, float* wf, int* sb, float* wb){
  int e = blockIdx.x*256+threadIdx.x; if(e>=E) return;
  int r = ei[e], c = ei[E+e];
  float w = WEDGE * dinv[r]*dinv[c];
  int pf = atomicAdd(&curf[r],1); sf[pf]=c; wf[pf]=w;
  int pb = atomicAdd(&curb[c],1); sb[pb]=r; wb[pb]=w;
}

// ---------------- layer 1 (scalar cheb) ----------------
__global__ void k_sprop(const float* __restrict__ t1f, const float* __restrict__ t0f, float* df,
                        const float* __restrict__ t1b, const float* __restrict__ t0b, float* db,
                        const int* __restrict__ offf, const int* __restrict__ sfa, const float* __restrict__ wfa,
                        const int* __restrict__ offb, const int* __restrict__ sba, const float* __restrict__ wba,
                        int N){
  int i = blockIdx.x*256+threadIdx.x;
  int dir = 0; if (i >= N){ i -= N; dir = 1; }
  if (i >= N) return;
  const float* t1; const float* t0; float* d; const int* off; const int* s; const float* w;
  if (dir==0){ t1=t1f; t0=t0f; d=df; off=offf; s=sfa; w=wfa; }
  else       { t1=t1b; t0=t0b; d=db; off=offb; s=sba; w=wba; }
  float a = WLOOP * t1[i];
  int e1 = off[i+1];
  for (int e=off[i]; e<e1; ++e) a += w[e]*t1[s[e]];
  d[i] = t0 ? (2.f*a - t0[i]) : a;
}

__global__ void k_expand(const float* __restrict__ x,
   const float* __restrict__ cf1, const float* __restrict__ cf2, const float* __restrict__ cf3, const float* __restrict__ cf4,
   const float* __restrict__ cb1, const float* __restrict__ cb2, const float* __restrict__ cb3, const float* __restrict__ cb4,
   const float* __restrict__ W1f, const float* __restrict__ b1f,
   const float* __restrict__ W1b, const float* __restrict__ b1b,
   u16* __restrict__ T, int N){
  __shared__ float swf[640], swb[640], sbias[128];
  int tid = threadIdx.x;
  for (int i=tid;i<640;i+=256){ swf[i]=W1f[i]; swb[i]=W1b[i]; }
  if (tid<128) sbias[tid]=b1f[tid]+b1b[tid];
  __syncthreads();
  int j = tid & 127; int n = blockIdx.x*2 + (tid>>7);
  if (n>=N) return;
  float xx = x[n];
  float acc = sbias[j] + xx*(swf[j]+swb[j]);
  acc += cf1[n]*swf[128+j]; acc += cf2[n]*swf[256+j]; acc += cf3[n]*swf[384+j]; acc += cf4[n]*swf[512+j];
  acc += cb1[n]*swb[128+j]; acc += cb2[n]*swb[256+j]; acc += cb3[n]*swb[384+j]; acc += cb4[n]*swb[512+j];
  T[(size_t)n*1152 + j] = f2bf(fmaxf(acc,0.f));
}

// ---------------- layer 2 vector props (bf16 rows, fp32 accum) ----------------
__global__ void k_vprop(u16* __restrict__ T,
   const int* __restrict__ offf, const int* __restrict__ sfa, const float* __restrict__ wfa,
   const int* __restrict__ offb, const int* __restrict__ sba, const float* __restrict__ wba,
   int ssf, int dsf, int psf, int ssb, int dsb, int psb, int N){
  int gid = blockIdx.x*256 + threadIdx.x;
  int wid = gid>>6, l = threadIdx.x & 63;
  int dir = 0; if (wid >= N){ wid -= N; dir = 1; }
  if (wid >= N) return;
  const int* off; const int* s; const float* w; int ss,ds,ps;
  if (!dir){ off=offf;s=sfa;w=wfa;ss=ssf;ds=dsf;ps=psf; }
  else     { off=offb;s=sba;w=wba;ss=ssb;ds=dsb;ps=psb; }
  u32 u = *(const u32*)(T + ((size_t)wid*1152 + ss*128) + 2*l);
  float a0 = WLOOP*bf2f(u&0xffff), a1 = WLOOP*bf2f(u>>16);
  int e1 = off[wid+1];
  for (int e=off[wid]; e<e1; ++e){
    int sn = s[e]; float we = w[e];
    u32 ug = *(const u32*)(T + ((size_t)sn*1152 + ss*128) + 2*l);
    a0 += we*bf2f(ug&0xffff); a1 += we*bf2f(ug>>16);
  }
  float r0=a0, r1=a1;
  if (ps >= 0){
    u32 up = *(const u32*)(T + ((size_t)wid*1152 + ps*128) + 2*l);
    r0 = 2.f*a0 - bf2f(up&0xffff); r1 = 2.f*a1 - bf2f(up>>16);
  }
  *(u32*)(T + ((size_t)wid*1152 + ds*128) + 2*l) = ((u32)f2bf(r1)<<16) | (u32)f2bf(r0);
}

// ---------------- weight prep ----------------
__global__ void k_wprep(const float* __restrict__ W2f, const float* __restrict__ W2b,
                        const float* __restrict__ b2f, const float* __restrict__ b2b,
                        u16* __restrict__ Wt, float* __restrict__ bias2){
  int i = blockIdx.x*256+threadIdx.x;
  if (i < 512) bias2[i] = b2f[i]+b2b[i];
  if (i >= 512*1152) return;
  int j = i/1152, kc = i - j*1152;
  int s2 = kc>>7, c = kc&127;
  float v;
  if (s2==0)      v = W2f[c*512+j] + W2b[c*512+j];
  else if (s2<5)  v = W2f[(s2*128+c)*512 + j];
  else            v = W2b[((s2-4)*128+c)*512 + j];
  Wt[i] = f2bf(v);
}

// ---------------- pooled GEMM: T[M x 1152] @ Wt^T -> relu -> segment-sum ----------------
__global__ __launch_bounds__(256) void k_gemm(const u16* __restrict__ T, const u16* __restrict__ Wt,
                        const float* __restrict__ bias2, const int* __restrict__ batch,
                        float* __restrict__ outp, int Mvalid){
  __shared__ u16 Al[128*64];
  __shared__ u16 Bl[128*64];
  int bid = blockIdx.x;
  int bn = bid & 3, bm = bid >> 2;
  int tid = threadIdx.x, w = tid>>6, l = tid&63;
  int wr = w>>1, wc = w&1;
  int hi = l>>4, lo = l&15;

  f32x4 acc[4][4];
  #pragma unroll
  for (int m=0;m<4;m++)
    #pragma unroll
    for (int n=0;n<4;n++){ acc[m][n][0]=0.f; acc[m][n][1]=0.f; acc[m][n][2]=0.f; acc[m][n][3]=0.f; }

  int ldsoff[4], gA[4], gB[4];
  #pragma unroll
  for (int i=0;i<4;i++){
    int r0 = (w*4+i)*8;
    int r  = r0 + (l>>3);
    int sc = (l&7) ^ (r&7);            // source chunk pre-swizzle (T2 / G4)
    ldsoff[i] = r0*64;
    gA[i] = (bm*128 + r)*1152 + sc*8;
    gB[i] = (bn*128 + r)*1152 + sc*8;
  }
  int rA[4], rB[4];
  #pragma unroll
  for (int m=0;m<4;m++){ rA[m] = wr*64 + m*16 + lo; rB[m] = wc*64 + m*16 + lo; }

  for (int kk=0; kk<1152; kk+=64){
    __syncthreads();
    #pragma unroll
    for (int i=0;i<4;i++){
      async16(&Al[ldsoff[i]], T  + gA[i] + kk);
      async16(&Bl[ldsoff[i]], Wt + gB[i] + kk);
    }
    __syncthreads();
    #pragma unroll
    for (int ks=0; ks<2; ++ks){
      bf16x8 af[4], bfr[4];
      #pragma unroll
      for (int m=0;m<4;m++){
        int ch = (ks*4 + hi) ^ (rA[m]&7);
        af[m] = *(const bf16x8*)&Al[rA[m]*64 + ch*8];
      }
      #pragma unroll
      for (int n=0;n<4;n++){
        int ch = (ks*4 + hi) ^ (rB[n]&7);
        bfr[n] = *(const bf16x8*)&Bl[rB[n]*64 + ch*8];
      }
      #pragma unroll
      for (int m=0;m<4;m++)
        #pragma unroll
        for (int n=0;n<4;n++)
          acc[m][n] = __builtin_amdgcn_mfma_f32_16x16x32_bf16(af[m], bfr[n], acc[m][n], 0, 0, 0);
    }
  }

  // epilogue: bias + relu + segment-sum into pool (batch sorted -> run-length combine)
  #pragma unroll
  for (int m=0;m<4;m++){
    int rbase = bm*128 + wr*64 + m*16 + hi*4;
    #pragma unroll
    for (int n=0;n<4;n++){
      int col = bn*128 + wc*64 + n*16 + lo;
      float bc = bias2[col];
      f32x4 v = acc[m][n];
      int cur = -1; float ssum = 0.f;
      #pragma unroll
      for (int j2=0;j2<4;j2++){
        int row = rbase + j2;
        if (row < Mvalid){
          float val = fmaxf(v[j2] + bc, 0.f);
          int bg = batch[row];
          if (bg != cur){ if (cur >= 0) atomicAdd(&outp[(cur<<9) + col], ssum); cur = bg; ssum = 0.f; }
          ssum += val;
        }
      }
      if (cur >= 0) atomicAdd(&outp[(cur<<9) + col], ssum);
    }
  }
}

// per-block LDS histogram: ~200 global atomics total instead of 100k
__global__ void k_count(const int* __restrict__ batch, int* cg, int N){
  __shared__ int sh[64];
  int t = threadIdx.x;
  if (t < 64) sh[t] = 0;
  __syncthreads();
  int base = blockIdx.x*1024;
  #pragma unroll
  for (int i = base + t; i < base + 1024; i += 256){
    if (i < N) atomicAdd(&sh[batch[i]], 1);
  }
  __syncthreads();
  if (t < 64){ int v = sh[t]; if (v) atomicAdd(&cg[t], v); }
}

__global__ void k_div(float* out, const int* __restrict__ cg, int total){
  int i = blockIdx.x*256+threadIdx.x; if (i>=total) return;
  int g = i>>9; out[i] /= fmaxf((float)cg[g], 1.f);
}

extern "C" void kernel_launch(void* const* d_in, const int* in_sizes, int n_in,
                              void* d_out, int out_size, void* d_ws, size_t ws_size,
                              hipStream_t stream) {
  const float* x   = (const float*)d_in[0];
  const int*   ei  = (const int*)d_in[1];
  const int*   bat = (const int*)d_in[2];
  const float* W1f = (const float*)d_in[3];
  const float* b1f = (const float*)d_in[4];
  const float* W1b = (const float*)d_in[5];
  const float* b1b = (const float*)d_in[6];
  const float* W2f = (const float*)d_in[7];
  const float* b2f = (const float*)d_in[8];
  const float* W2b = (const float*)d_in[9];
  const float* b2b = (const float*)d_in[10];

  const int N  = in_sizes[0];
  const int E  = in_sizes[1] / 2;
  const int NP = ((N + 127)/128)*128;

  // ---- ws layout ----
  size_t p = 0;
  auto A = [&](size_t sz){ size_t r = p; p += (sz + 255) & ~(size_t)255; return r; };
  size_t o_cnt  = A(2*(size_t)N*4);          // cnt_f | cnt_b
  size_t o_offf = A(((size_t)N+1)*4);
  size_t o_offb = A(((size_t)N+1)*4);
  size_t o_curf = A((size_t)N*4);
  size_t o_curb = A((size_t)N*4);
  size_t o_bsum = A(512*4);
  size_t o_dinv = A((size_t)N*4);
  size_t o_csf  = A((size_t)E*4);
  size_t o_cwf  = A((size_t)E*4);
  size_t o_csb  = A((size_t)E*4);
  size_t o_cwb  = A((size_t)E*4);
  size_t o_cf   = A(8*(size_t)N*4);          // cf1..4, cb1..4
  size_t o_Wt   = A((size_t)512*1152*2);
  size_t o_b2   = A(512*4);
  size_t o_cg   = A(64*4);
  size_t o_T    = A((size_t)NP*1152*2);
  if (p > ws_size) return;  // ws too small: bail (visible as validation failure)

  char* ws = (char*)d_ws;
  int*   cnt_f = (int*)(ws + o_cnt);
  int*   cnt_b = cnt_f + N;
  int*   off_f = (int*)(ws + o_offf);
  int*   off_b = (int*)(ws + o_offb);
  int*   cur_f = (int*)(ws + o_curf);
  int*   cur_b = (int*)(ws + o_curb);
  int*   bsum  = (int*)(ws + o_bsum);
  float* dinv  = (float*)(ws + o_dinv);
  int*   csf   = (int*)(ws + o_csf);
  float* cwf   = (float*)(ws + o_cwf);
  int*   csb   = (int*)(ws + o_csb);
  float* cwb   = (float*)(ws + o_cwb);
  float* cf1   = (float*)(ws + o_cf);
  float* cf2   = cf1 + N; float* cf3 = cf2 + N; float* cf4 = cf3 + N;
  float* cb1   = cf4 + N; float* cb2 = cb1 + N; float* cb3 = cb2 + N; float* cb4 = cb3 + N;
  u16*   Wt    = (u16*)(ws + o_Wt);
  float* bias2 = (float*)(ws + o_b2);
  int*   cg    = (int*)(ws + o_cg);
  u16*   T     = (u16*)(ws + o_T);
  float* outp  = (float*)d_out;

  const int nbN = (N + 255)/256;
  const int nbE = (E + 255)/256;
  const int nb2N = (2*N + 255)/256;

  // zero-init accumulators + T pad rows
  hipMemsetAsync(cnt_f, 0, 2*(size_t)N*4, stream);
  hipMemsetAsync(cg, 0, 64*4, stream);
  hipMemsetAsync(d_out, 0, (size_t)out_size*4, stream);
  if (NP > N) hipMemsetAsync(T + (size_t)N*1152, 0, (size_t)(NP-N)*1152*2, stream);

  // graph prep
  k_hist<<<nbE,256,0,stream>>>(ei, E, cnt_f, cnt_b);
  k_dinv<<<nbN,256,0,stream>>>(cnt_f, dinv, N);
  k_scanA<<<nbN,256,0,stream>>>(cnt_f, off_f, bsum, N);
  k_scanB<<<1,512,0,stream>>>(bsum, nbN, off_f + N);
  k_scanC<<<nbN,256,0,stream>>>(off_f, bsum, N, cur_f);
  k_scanA<<<nbN,256,0,stream>>>(cnt_b, off_b, bsum, N);
  k_scanB<<<1,512,0,stream>>>(bsum, nbN, off_b + N);
  k_scanC<<<nbN,256,0,stream>>>(off_b, bsum, N, cur_b);
  k_fill<<<nbE,256,0,stream>>>(ei, E, dinv, cur_f, cur_b, csf, cwf, csb, cwb);

  // layer 1 scalar chebyshev
  k_sprop<<<nb2N,256,0,stream>>>(x,   nullptr, cf1,  x,   nullptr, cb1, off_f,csf,cwf, off_b,csb,cwb, N);
  k_sprop<<<nb2N,256,0,stream>>>(cf1, x,       cf2,  cb1, x,       cb2, off_f,csf,cwf, off_b,csb,cwb, N);
  k_sprop<<<nb2N,256,0,stream>>>(cf2, cf1,     cf3,  cb2, cb1,     cb3, off_f,csf,cwf, off_b,csb,cwb, N);
  k_sprop<<<nb2N,256,0,stream>>>(cf3, cf2,     cf4,  cb3, cb2,     cb4, off_f,csf,cwf, off_b,csb,cwb, N);
  k_expand<<<(N+1)/2,256,0,stream>>>(x, cf1,cf2,cf3,cf4, cb1,cb2,cb3,cb4, W1f,b1f,W1b,b1b, T, N);

  // weights for fused GEMM
  k_wprep<<<(512*1152+255)/256,256,0,stream>>>(W2f, W2b, b2f, b2b, Wt, bias2);

  // layer 2 vector chebyshev: slots 0=h, 1..4=fwd, 5..8=bwd
  const int vb = (2*N*64 + 255)/256;
  k_vprop<<<vb,256,0,stream>>>(T, off_f,csf,cwf, off_b,csb,cwb, 0,1,-1, 0,5,-1, N);
  k_vprop<<<vb,256,0,stream>>>(T, off_f,csf,cwf, off_b,csb,cwb, 1,2, 0, 5,6, 0, N);
  k_vprop<<<vb,256,0,stream>>>(T, off_f,csf,cwf, off_b,csb,cwb, 2,3, 1, 6,7, 5, N);
  k_vprop<<<vb,256,0,stream>>>(T, off_f,csf,cwf, off_b,csb,cwb, 3,4, 2, 7,8, 6, N);

  // pooled GEMM + mean
  k_count<<<(N+1023)/1024,256,0,stream>>>(bat, cg, N);
  k_gemm<<<(NP/128)*4,256,0,stream>>>(T, Wt, bias2, bat, outp, N);
  k_div<<<(out_size+255)/256,256,0,stream>>>(outp, cg, out_size);
}